// Round 1
// baseline (467.014 us; speedup 1.0000x reference)
//
#include <hip/hip_runtime.h>
#include <hip/hip_bf16.h>
#include <string.h>

// Problem constants
#define BB 8
#define SS 2048
#define HH 8
#define DKK 64
#define HD 512   // H*DK
#define DM 512

typedef __attribute__((ext_vector_type(8))) short short8;   // 8 bf16 in 4 VGPRs
typedef __attribute__((ext_vector_type(4))) float floatx4;  // MFMA C/D

__device__ __forceinline__ short f2bf(float f) {
    __hip_bfloat16 h = __float2bfloat16(f);  // RNE
    short s;
    __builtin_memcpy(&s, &h, 2);
    return s;
}

// ---------------------------------------------------------------------------
// prep: cast q/k/v -> bf16, build WqT[512][64], WoT[512][512] (bf16, transposed)
// ---------------------------------------------------------------------------
__global__ void prep_kernel(const float* __restrict__ q, const float* __restrict__ k,
                            const float* __restrict__ v, const float* __restrict__ Wq,
                            const float* __restrict__ Wo,
                            short* __restrict__ qb, short* __restrict__ kb,
                            short* __restrict__ vb, short* __restrict__ WqT,
                            short* __restrict__ WoT) {
    int idx = blockIdx.x * 256 + threadIdx.x;            // 0 .. 1048575
    if (idx < BB * SS * DKK) {
        qb[idx] = f2bf(q[idx]);
        kb[idx] = f2bf(k[idx]);
        vb[idx] = f2bf(v[idx]);
    }
    if (idx < HD * DKK) {                                 // 32768
        int o = idx >> 6, i = idx & 63;                   // WqT[o][i] = Wq[i][o]
        WqT[idx] = f2bf(Wq[i * HD + o]);
    }
    if (idx < DM * HD) {                                  // 262144
        int o = idx >> 9, i = idx & 511;                  // WoT[o][i] = Wo[i][o]
        WoT[idx] = f2bf(Wo[i * DM + o]);
    }
}

// ---------------------------------------------------------------------------
// maskbits: bit=1 where mask==1.0 (those positions get -inf). 1 bit per entry.
// layout: row (b*2048+s) has 2048 bits = 32 uint64, k ascending with bit index.
// ---------------------------------------------------------------------------
__global__ void maskbits_kernel(const float* __restrict__ mask,
                                unsigned long long* __restrict__ bits) {
    size_t idx = (size_t)blockIdx.x * 256 + threadIdx.x;  // < 33554432
    float val = mask[idx];
    unsigned long long bal = __ballot(val == 1.0f);
    if ((threadIdx.x & 63) == 0) bits[idx >> 6] = bal;
}

// ---------------------------------------------------------------------------
// Generic C = A * B^T + bias.  A:[M][K] bf16 row-major, Bt:[N][K] bf16 row-major.
// Block 256 thr = 4 waves in 2x2; tile 128x128; BK=64; 16x16x32 bf16 MFMA.
// OUT_F32: write float, else bf16.  BIAS_ROW: bias indexed by row (len M), else col.
// All dims here are multiples of 128/64 -> no bounds checks.
// ---------------------------------------------------------------------------
template <bool OUT_F32, bool BIAS_ROW>
__global__ __launch_bounds__(256, 2) void gemm_bt(
    const short* __restrict__ A, int lda, long sA,
    const short* __restrict__ Bt, int ldb, long sB,
    void* __restrict__ C, int ldc, long sC,
    const float* __restrict__ bias, int K) {
    const int bz = blockIdx.z;
    const short* Ab = A + (size_t)bz * sA;
    const short* Bb = Bt + (size_t)bz * sB;
    const int m0 = blockIdx.y * 128, n0 = blockIdx.x * 128;
    __shared__ __align__(16) short As[128 * 80];
    __shared__ __align__(16) short Bs[128 * 80];
    const int tid = threadIdx.x, lane = tid & 63, w = tid >> 6;
    const int c = lane & 15, Q = lane >> 4;
    const int wm = w >> 1, wn = w & 1;
    floatx4 acc[4][4] = {};

    for (int k0 = 0; k0 < K; k0 += 64) {
#pragma unroll
        for (int it = 0; it < 4; ++it) {
            int chunk = it * 256 + tid;          // 1024 chunks of 16B each side
            int row = chunk >> 3, c8 = chunk & 7;
            *(uint4*)&As[row * 80 + c8 * 8] =
                *(const uint4*)&Ab[(size_t)(m0 + row) * lda + k0 + c8 * 8];
            *(uint4*)&Bs[row * 80 + c8 * 8] =
                *(const uint4*)&Bb[(size_t)(n0 + row) * ldb + k0 + c8 * 8];
        }
        __syncthreads();
#pragma unroll
        for (int ks = 0; ks < 2; ++ks) {
            short8 af[4], bf[4];
#pragma unroll
            for (int mt = 0; mt < 4; ++mt)
                af[mt] = *(const short8*)&As[(wm * 64 + mt * 16 + c) * 80 + ks * 32 + 8 * Q];
#pragma unroll
            for (int nt = 0; nt < 4; ++nt)
                bf[nt] = *(const short8*)&Bs[(wn * 64 + nt * 16 + c) * 80 + ks * 32 + 8 * Q];
#pragma unroll
            for (int mt = 0; mt < 4; ++mt)
#pragma unroll
                for (int nt = 0; nt < 4; ++nt)
                    acc[mt][nt] = __builtin_amdgcn_mfma_f32_16x16x32_bf16(
                        af[mt], bf[nt], acc[mt][nt], 0, 0, 0);
        }
        __syncthreads();
    }
    // epilogue: row = m0+wm*64+mt*16+4Q+r, col = n0+wn*64+nt*16+c
#pragma unroll
    for (int mt = 0; mt < 4; ++mt)
#pragma unroll
        for (int nt = 0; nt < 4; ++nt) {
            int col = n0 + wn * 64 + nt * 16 + c;
            float bc = BIAS_ROW ? 0.f : bias[col];
#pragma unroll
            for (int r = 0; r < 4; ++r) {
                int row = m0 + wm * 64 + mt * 16 + 4 * Q + r;
                float val = acc[mt][nt][r] + (BIAS_ROW ? bias[row] : bc);
                if (OUT_F32)
                    ((float*)C)[(size_t)bz * sC + (size_t)row * ldc + col] = val;
                else
                    ((short*)C)[(size_t)bz * sC + (size_t)row * ldc + col] = f2bf(val);
            }
        }
}

// ---------------------------------------------------------------------------
// Flash attention.  Block = 512 thr (8 waves), one (b,h,128-row Q tile).
// qh,kh: [b][s][hd] bf16.  vhT: [b][hd][s] bf16.  y: [b][s][hd] bf16.
// LDS: Ks (stride 80) aliased with Ps (stride 136); Vs (stride 144) after.
// ---------------------------------------------------------------------------
__global__ __launch_bounds__(512, 4) void fa_kernel(
    const short* __restrict__ qh, const short* __restrict__ kh,
    const short* __restrict__ vhT, const unsigned* __restrict__ mbits,
    short* __restrict__ y) {
    const int qt = blockIdx.x;         // 0..15
    const int bh = blockIdx.y;         // 0..63
    const int b = bh >> 3, h = bh & 7;
    const int tid = threadIdx.x, lane = tid & 63, w = tid >> 6;
    const int c = lane & 15, Q = lane >> 4;

    __shared__ __align__(16) short smem[26624];  // 53,248 B
    short* Ks = smem;                  // 128 rows, stride 80  (QK phase)
    short* Ps = smem;                  // 128 rows, stride 136 (aliases Ks, after barrier)
    short* Vs = smem + 17408;          // 64 rows, stride 144

    // Q fragments, loaded once (A-frag: m=lane&15 within wave's 16 rows, k=8Q+j+32ks)
    const int qrow = qt * 128 + w * 16 + c;
    const short* qbase = qh + ((size_t)(b * SS + qrow)) * HD + h * DKK;
    short8 qf0 = *(const short8*)(qbase + 8 * Q);
    short8 qf1 = *(const short8*)(qbase + 32 + 8 * Q);

    floatx4 o_acc[4] = {};
    float m_i[4], l_i[4];
#pragma unroll
    for (int r = 0; r < 4; ++r) { m_i[r] = -INFINITY; l_i[r] = 0.f; }

    for (int kt = 0; kt < 16; ++kt) {
        // ---- stage K tile (128x64) and V^T tile (64x128) ----
#pragma unroll
        for (int it = 0; it < 2; ++it) {
            int chunk = it * 512 + tid;     // 1024 chunks
            int row = chunk >> 3, c8 = chunk & 7;
            *(uint4*)&Ks[row * 80 + c8 * 8] =
                *(const uint4*)(kh + ((size_t)(b * SS + kt * 128 + row)) * HD + h * DKK + c8 * 8);
        }
#pragma unroll
        for (int it = 0; it < 4; ++it) {
            int chunk = it * 512 + tid;     // 2048 chunks... (64 rows * 16 chunks = 1024)*2? no: 64*16=1024 -> 2 its of 512
            if (it < 2) {
                int row = chunk >> 4, c16 = chunk & 15;
                *(uint4*)&Vs[row * 144 + c16 * 8] =
                    *(const uint4*)(vhT + ((size_t)(b * HD + h * DKK + row)) * SS + kt * 128 + c16 * 8);
            }
        }
        __syncthreads();

        // ---- S = Q K^T (accumulate fp32) ----
        floatx4 s_acc[8];
#pragma unroll
        for (int jt = 0; jt < 8; ++jt) {
            short8 k0 = *(const short8*)&Ks[(jt * 16 + c) * 80 + 8 * Q];
            short8 k1 = *(const short8*)&Ks[(jt * 16 + c) * 80 + 32 + 8 * Q];
            floatx4 s = {};
            s = __builtin_amdgcn_mfma_f32_16x16x32_bf16(qf0, k0, s, 0, 0, 0);
            s = __builtin_amdgcn_mfma_f32_16x16x32_bf16(qf1, k1, s, 0, 0, 0);
            s_acc[jt] = s;
        }
        __syncthreads();   // all waves done reading Ks; Ps may now alias it

        // ---- mask + online softmax, write P (bf16) to per-wave-private LDS rows ----
        const unsigned* mb = mbits + ((size_t)(b * SS + qt * 128 + w * 16)) * 64 + kt * 4;
#pragma unroll
        for (int r = 0; r < 4; ++r) {
            uint4 mr = *(const uint4*)(mb + (size_t)(4 * Q + r) * 64);
            unsigned mw[4] = {mr.x, mr.y, mr.z, mr.w};
            float sv[8];
            float mx = -INFINITY;
#pragma unroll
            for (int jt = 0; jt < 8; ++jt) {
                bool msk = (mw[jt >> 1] >> (((jt & 1) << 4) + c)) & 1u;
                float val = s_acc[jt][r] * 0.125f;
                sv[jt] = msk ? -INFINITY : val;
                mx = fmaxf(mx, sv[jt]);
            }
#pragma unroll
            for (int off = 1; off < 16; off <<= 1) mx = fmaxf(mx, __shfl_xor(mx, off));
            float mnew = fmaxf(m_i[r], mx);
            float msafe = (mnew == -INFINITY) ? 0.f : mnew;
            float al = __expf(m_i[r] - msafe);
            float ps = 0.f;
#pragma unroll
            for (int jt = 0; jt < 8; ++jt) {
                float p = __expf(sv[jt] - msafe);
                ps += p;
                Ps[(w * 16 + 4 * Q + r) * 136 + jt * 16 + c] = f2bf(p);
            }
#pragma unroll
            for (int off = 1; off < 16; off <<= 1) ps += __shfl_xor(ps, off);
            l_i[r] = l_i[r] * al + ps;
            m_i[r] = mnew;
#pragma unroll
            for (int nt = 0; nt < 4; ++nt) o_acc[nt][r] = o_acc[nt][r] * al;
        }
        asm volatile("s_waitcnt lgkmcnt(0)" ::: "memory");

        // ---- O += P V ----
        short8 pa[4];
#pragma unroll
        for (int ks = 0; ks < 4; ++ks)
            pa[ks] = *(const short8*)&Ps[(w * 16 + c) * 136 + ks * 32 + 8 * Q];
#pragma unroll
        for (int nt = 0; nt < 4; ++nt)
#pragma unroll
            for (int ks = 0; ks < 4; ++ks) {
                short8 vf = *(const short8*)&Vs[(nt * 16 + c) * 144 + ks * 32 + 8 * Q];
                o_acc[nt] = __builtin_amdgcn_mfma_f32_16x16x32_bf16(pa[ks], vf, o_acc[nt], 0, 0, 0);
            }
        __syncthreads();
    }

    // ---- epilogue: O/l -> y bf16 ----
#pragma unroll
    for (int r = 0; r < 4; ++r) {
        float inv = 1.0f / l_i[r];
        int row = qt * 128 + w * 16 + 4 * Q + r;
#pragma unroll
        for (int nt = 0; nt < 4; ++nt) {
            float val = o_acc[nt][r] * inv;
            y[((size_t)(b * SS + row)) * HD + h * DKK + nt * 16 + c] = f2bf(val);
        }
    }
}

// ---------------------------------------------------------------------------
extern "C" void kernel_launch(void* const* d_in, const int* in_sizes, int n_in,
                              void* d_out, int out_size, void* d_ws, size_t ws_size,
                              hipStream_t stream) {
    const float* q    = (const float*)d_in[0];
    const float* k    = (const float*)d_in[1];
    const float* v    = (const float*)d_in[2];
    const float* mask = (const float*)d_in[3];
    const float* Wq   = (const float*)d_in[4];
    const float* bq   = (const float*)d_in[5];
    const float* Wo   = (const float*)d_in[6];
    const float* bo   = (const float*)d_in[7];

    char* ws = (char*)d_ws;
    const size_t MB = 1ull << 20;
    short* WqT = (short*)(ws + 0 * MB);    // 64 KB
    short* WoT = (short*)(ws + 1 * MB);    // 512 KB
    short* qb  = (short*)(ws + 2 * MB);    // 2 MB
    short* kb  = (short*)(ws + 4 * MB);    // 2 MB
    short* vb  = (short*)(ws + 6 * MB);    // 2 MB
    short* qh  = (short*)(ws + 8 * MB);    // 16 MB  [b][s][hd]
    short* kh  = (short*)(ws + 24 * MB);   // 16 MB  [b][s][hd]
    short* vhT = (short*)(ws + 40 * MB);   // 16 MB  [b][hd][s]
    unsigned long long* bits = (unsigned long long*)(ws + 56 * MB);  // 4 MB
    short* yb  = (short*)(ws + 60 * MB);   // 16 MB  [b][s][hd]
    float* out = (float*)d_out;

    prep_kernel<<<4096, 256, 0, stream>>>(q, k, v, Wq, Wo, qb, kb, vb, WqT, WoT);
    maskbits_kernel<<<131072, 256, 0, stream>>>(mask, bits);

    // qh = q @ Wq + bq ; kh = k @ Wq + bq   (M=16384, N=512, K=64)
    gemm_bt<false, false><<<dim3(4, 128, 1), 256, 0, stream>>>(
        qb, 64, 0, WqT, 64, 0, (void*)qh, 512, 0, bq, 64);
    gemm_bt<false, false><<<dim3(4, 128, 1), 256, 0, stream>>>(
        kb, 64, 0, WqT, 64, 0, (void*)kh, 512, 0, bq, 64);
    // vhT[b][hd][s] = (Wq^T v_b^T) + bq (row bias): M=512, N=2048, K=64, batched over b
    gemm_bt<false, true><<<dim3(16, 4, BB), 256, 0, stream>>>(
        WqT, 64, 0, vb, 64, (long)SS * DKK, (void*)vhT, SS, (long)HD * SS, bq, 64);

    fa_kernel<<<dim3(16, 64, 1), 512, 0, stream>>>(qh, kh, vhT, (const unsigned*)bits, yb);

    // out = y @ Wo + bo  (M=16384, N=512, K=512), fp32 out
    gemm_bt<true, false><<<dim3(4, 128, 1), 256, 0, stream>>>(
        yb, 512, 0, WoT, 512, 0, (void*)out, 512, 0, bo, 512);
}